// Round 16
// baseline (544.774 us; speedup 1.0000x reference)
//
#include <hip/hip_runtime.h>
#include <math.h>

#define N_NODES 20000
#define N_EDGES 160000
#define DIM_IN  128
#define HIDDEN  96
#define NH      6
#define HD      576      // NH*HIDDEN
#define LDROW   704      // bf16 row stride: Q(576)|S(96)|pad(32) = 11 lines
#define KVF8LD  1152     // fp8 row stride BYTES: K(576)|V(576) = 9 lines
#define NALL    1824     // concat QKVS weight cols
#define NGRAPH  512
#define NCLS    128
#define CHUNK   32       // edges per softmax chunk
#define SLD     104      // bf16 LDS stage row stride (ushorts)
#define BSTR    112      // fp8 LDS stage row stride (bytes, mult of 16)

typedef unsigned short ushort_t;
typedef unsigned char uchar_t;
typedef __attribute__((ext_vector_type(8))) short bf16x8;
typedef __attribute__((ext_vector_type(4))) float f32x4;
typedef __attribute__((ext_vector_type(2))) float f32x2;

static __device__ __forceinline__ ushort_t f2bf(float f) {
    unsigned int u = __float_as_uint(f);
    return (ushort_t)((u + 0x7fffu + ((u >> 16) & 1u)) >> 16);  // RNE
}
static __device__ __forceinline__ float bfs(ushort_t u) { return __uint_as_float((unsigned int)u << 16); }
static __device__ __forceinline__ float bflo(unsigned int u) { return __uint_as_float(u << 16); }
static __device__ __forceinline__ float bfhi(unsigned int u) { return __uint_as_float(u & 0xffff0000u); }

// ---------------------------------------------------------------------------
// Fused prep: x->bf16 cast | edge degree histogram | graph boundaries.
// Block-range partitioned single launch.
// ---------------------------------------------------------------------------
#define PREP_CVT_BLOCKS 10000   // 20000*128/256
#define PREP_DEG_BLOCKS 625     // 160000/256
#define PREP_GB_BLOCKS  3       // ceil((NGRAPH+1)/256)
__global__ void k_prep(const float* __restrict__ x, ushort_t* __restrict__ xb,
                       const int* __restrict__ edst, int* __restrict__ deg,
                       const int* __restrict__ batch, int* __restrict__ gbound)
{
    int b = blockIdx.x;
    if (b < PREP_CVT_BLOCKS) {
        int i = b * 256 + threadIdx.x;
        if (i < N_NODES * DIM_IN) xb[i] = f2bf(x[i]);
    } else if (b < PREP_CVT_BLOCKS + PREP_DEG_BLOCKS) {
        int e = (b - PREP_CVT_BLOCKS) * 256 + threadIdx.x;
        if (e < N_EDGES) atomicAdd(&deg[edst[e]], 1);
    } else {
        int g = (b - PREP_CVT_BLOCKS - PREP_DEG_BLOCKS) * 256 + threadIdx.x;
        if (g <= NGRAPH) {
            int lo = 0, hi = N_NODES;
            while (lo < hi) {
                int mid = (lo + hi) >> 1;
                if (batch[mid] < g) lo = mid + 1; else hi = mid;
            }
            gbound[g] = lo;
        }
    }
}

// All 5 layers' transposed concat bf16 weights in one launch. grid.y = layer.
__global__ void k_cvt_wT_all(
    const float* __restrict__ Wq1, const float* __restrict__ Wk1,
    const float* __restrict__ Wv1, const float* __restrict__ Ws1,
    const float* __restrict__ Wq_r, const float* __restrict__ Wk_r,
    const float* __restrict__ Wv_r, const float* __restrict__ Ws_r,
    ushort_t* __restrict__ Wb0, ushort_t* __restrict__ Wbr)
{
    const int L = blockIdx.y;
    const int K = (L == 0) ? DIM_IN : HIDDEN;
    int i = blockIdx.x * blockDim.x + threadIdx.x;
    if (i >= K * NALL) return;
    const float *Wq, *Wk, *Wv, *Ws; ushort_t* dst;
    if (L == 0) { Wq = Wq1; Wk = Wk1; Wv = Wv1; Ws = Ws1; dst = Wb0; }
    else {
        int j = L - 1;
        Wq = Wq_r + (size_t)j * HIDDEN * HD; Wk = Wk_r + (size_t)j * HIDDEN * HD;
        Wv = Wv_r + (size_t)j * HIDDEN * HD; Ws = Ws_r + (size_t)j * HIDDEN * HIDDEN;
        dst = Wbr + (size_t)j * HIDDEN * NALL;
    }
    int n = i / K, k = i - n * K;
    float v;
    if (n < 576)       v = Wq[(size_t)k * HD + n];
    else if (n < 1152) v = Wk[(size_t)k * HD + (n - 576)];
    else if (n < 1728) v = Wv[(size_t)k * HD + (n - 1152)];
    else               v = Ws[(size_t)k * HIDDEN + (n - 1728)];
    dst[i] = f2bf(v);
}

// ---------------------------------------------------------------------------
// bf16 MFMA fused QKVS projection. Block tile 256(M) x 96(N), 4 waves stacked
// vertically: wave w owns rows [w*64, w*64+64) x all 96 cols = 4x6 MFMA tiles
// (72 MFMA/wave, 288/block). B staged once in LDS; A direct from global.
// Epilogue: two 128-row passes through the same LDS. K/V regions emit
// fp8-e4m3 into kvf8 [K|V]; Q/S bf16 into kvqs [Q|S].
// ---------------------------------------------------------------------------
template<int KDIM>
__global__ __launch_bounds__(256) void gemm_qkvs_mfma(
    const ushort_t* __restrict__ A, int M,
    const ushort_t* __restrict__ WbT,
    const float* __restrict__ bq, const float* __restrict__ bk,
    const float* __restrict__ bv, const float* __restrict__ bs,
    ushort_t* __restrict__ kvqs, uchar_t* __restrict__ kvf8)
{
    constexpr int LDB = KDIM + 8;       // padded B stride
    constexpr int K8  = KDIM >> 3;
    __shared__ __align__(16) ushort_t smem[128 * SLD];   // 26.6 KB (B stage / out stage)
    const int t    = threadIdx.x;
    const int lane = t & 63;
    const int w    = t >> 6;            // wave id = row group 0..3
    const int quad = lane >> 4;
    const int l16  = lane & 15;
    const int m0   = blockIdx.y * 256;
    const int rb   = blockIdx.x;        // 0..18
    const int n0   = rb * 96;

    // cooperative B stage: 96 cols x KDIM (96*LDB <= 128*SLD for K<=128)
    for (int idx = t; idx < 96 * K8; idx += 256) {
        int c = idx / K8, kc = idx - c * K8;
        uint4 v = *(const uint4*)(WbT + (size_t)(n0 + c) * KDIM + kc * 8);
        *(uint4*)(&smem[c * LDB + kc * 8]) = v;
    }

    // direct-global A fragment pointers (row-clamped for OOB M)
    const ushort_t* Arow[4];
    #pragma unroll
    for (int i = 0; i < 4; i++) {
        int row = m0 + w * 64 + i * 16 + l16;
        row = min(row, M - 1);
        Arow[i] = A + (size_t)row * KDIM + quad * 8;
    }
    __syncthreads();

    f32x4 acc[4][6] = {};
    #pragma unroll
    for (int ks = 0; ks < KDIM; ks += 32) {
        bf16x8 af[4], bfv[6];
        #pragma unroll
        for (int i = 0; i < 4; i++) af[i] = *(const bf16x8*)(Arow[i] + ks);
        #pragma unroll
        for (int j = 0; j < 6; j++)
            bfv[j] = *(const bf16x8*)(&smem[(j * 16 + l16) * LDB + ks + quad * 8]);
        #pragma unroll
        for (int i = 0; i < 4; i++)
            #pragma unroll
            for (int j = 0; j < 6; j++)
                acc[i][j] = __builtin_amdgcn_mfma_f32_16x16x32_bf16(af[i], bfv[j], acc[i][j], 0, 0, 0);
    }

    // region select (boundaries are multiples of 96)
    int region; const float* biasp;
    if (rb < 6)       { region = 0; biasp = bq; }
    else if (rb < 12) { region = 1; biasp = bk; }
    else if (rb < 18) { region = 2; biasp = bv; }
    else              { region = 3; biasp = bs; }
    const int colbase = (region == 3) ? 0 : (rb - region * 6) * 96;
    float bj[6];
    #pragma unroll
    for (int j = 0; j < 6; j++) bj[j] = biasp[colbase + j * 16 + l16];

    __syncthreads();   // done reading B from smem

    // epilogue: two 128-row passes; waves {0,1} then {2,3} stage their rows
    #pragma unroll
    for (int half = 0; half < 2; half++) {
        if ((w >> 1) == half) {
            int lr0 = (w & 1) * 64;   // local row base within 128-row stage
            if (region == 1 || region == 2) {
                uchar_t* bstage = (uchar_t*)smem;
                #pragma unroll
                for (int i = 0; i < 4; i++) {
                    #pragma unroll
                    for (int r = 0; r < 4; r++) {
                        int row = lr0 + i * 16 + quad * 4 + r;
                        #pragma unroll
                        for (int j = 0; j < 6; j++) {
                            float v = acc[i][j][r] + bj[j];
                            int pk = __builtin_amdgcn_cvt_pk_fp8_f32(v, v, 0, false);
                            bstage[row * BSTR + j * 16 + l16] = (uchar_t)(pk & 0xff);
                        }
                    }
                }
            } else {
                #pragma unroll
                for (int i = 0; i < 4; i++) {
                    #pragma unroll
                    for (int r = 0; r < 4; r++) {
                        int row = lr0 + i * 16 + quad * 4 + r;
                        #pragma unroll
                        for (int j = 0; j < 6; j++)
                            smem[row * SLD + j * 16 + l16] = f2bf(acc[i][j][r] + bj[j]);
                    }
                }
            }
        }
        __syncthreads();
        if (region == 1 || region == 2) {
            const uchar_t* bstage = (const uchar_t*)smem;
            const int c0 = (rb - 6) * 96;   // 0..1056 spans K|V contiguously
            for (int idx = t; idx < 128 * 6; idx += 256) {
                int r = idx / 6, v4 = idx - r * 6;
                int row = m0 + half * 128 + r;
                if (row < M)
                    *(uint4*)(kvf8 + (size_t)row * KVF8LD + c0 + v4 * 16) =
                        *(const uint4*)(bstage + r * BSTR + v4 * 16);
            }
        } else {
            int dstoff = (region == 0) ? n0 : 576;
            for (int idx = t; idx < 128 * 12; idx += 256) {
                int r = idx / 12, v = idx - r * 12;
                int row = m0 + half * 128 + r;
                if (row < M)
                    *(uint4*)(kvqs + (size_t)row * LDROW + dstoff + v * 8) =
                        *(const uint4*)(&smem[r * SLD + v * 8]);
            }
        }
        __syncthreads();
    }
}

// ---------------------------------------------------------------------------
// CSR construction (scan + scatter; degree done in k_prep)
// ---------------------------------------------------------------------------
__global__ __launch_bounds__(1024) void k_scan(const int* __restrict__ deg,
                                               int* __restrict__ row_ptr,
                                               int* __restrict__ cursor)
{
    __shared__ int part[1024];
    int t = threadIdx.x;
    const int chunk = (N_NODES + 1023) / 1024;  // 20
    int b = t * chunk;
    int s = 0;
    for (int i = 0; i < chunk; i++)
        if (b + i < N_NODES) s += deg[b + i];
    part[t] = s;
    __syncthreads();
    for (int o = 1; o < 1024; o <<= 1) {
        int v = (t >= o) ? part[t - o] : 0;
        __syncthreads();
        part[t] += v;
        __syncthreads();
    }
    int run = part[t] - s;
    for (int i = 0; i < chunk; i++) {
        if (b + i < N_NODES) {
            row_ptr[b + i] = run;
            cursor[b + i]  = run;
            run += deg[b + i];
        }
    }
    if (t == 1023) row_ptr[N_NODES] = part[1023];
}

__global__ void k_scatter(const int* __restrict__ esrc, const int* __restrict__ edst,
                          int* __restrict__ cursor, int* __restrict__ csrc)
{
    int e = blockIdx.x * blockDim.x + threadIdx.x;
    if (e < N_EDGES) {
        int pos = atomicAdd(&cursor[edst[e]], 1);
        csrc[pos] = esrc[e];
    }
}

// ---------------------------------------------------------------------------
// Fused per-destination-node attention (R14 version — best measured).
// fp8 K (pass 1) + fp8 V (pass 2) from kvf8; Q/S bf16 from kvqs.
// ---------------------------------------------------------------------------
__global__ __launch_bounds__(192) void node_attn(
    const ushort_t* __restrict__ kvqs, const uchar_t* __restrict__ kvf8,
    const int* __restrict__ row_ptr, const int* __restrict__ csrc,
    ushort_t* __restrict__ hb, float* __restrict__ hf)
{
    const int n = blockIdx.x;
    const int t = threadIdx.x;
    const int lane = t & 31;
    const int g = t >> 5;              // head group 0..5
    const int el = lane >> 2;          // edge slot 0..7
    const int qr = lane & 3;           // quarter 0..3

    __shared__ float Qs[HD];
    __shared__ float wbuf[CHUNK * NH];
    __shared__ int   srcs[CHUNK];
    __shared__ float m[NH], l[NH], scale[NH], linv[NH];
    __shared__ float arr[HD];

    const int beg = row_ptr[n], end = row_ptr[n + 1];
    const ushort_t* qk = kvqs + (size_t)n * LDROW;

    // vectorized Q stage: 72 threads x uint4 (8 bf16 each)
    if (t < 72) {
        uint4 v = *(const uint4*)(qk + t * 8);
        unsigned int uu[4] = {v.x, v.y, v.z, v.w};
        #pragma unroll
        for (int j = 0; j < 4; j++) {
            Qs[t * 8 + 2 * j]     = bflo(uu[j]);
            Qs[t * 8 + 2 * j + 1] = bfhi(uu[j]);
        }
    }
    if (t < NH) { m[t] = -1e30f; l[t] = 0.f; }

    // pass-2 ownership: t<144 owns d = 4t..4t+3 (all in head hh)
    const int d4 = 4 * t;
    const int hh = d4 / HIDDEN;        // valid for t<144
    float a[4] = {0.f, 0.f, 0.f, 0.f};
    const float qa = 0.10206207261596577f; // 1/sqrt(96)
    const uchar_t* vbase = kvf8 + 576 + d4;   // V at byte offset 576

    for (int cb = beg; cb < end; cb += CHUNK) {
        const int c = min(CHUNK, end - cb);
        __syncthreads();
        if (t < c) srcs[t] = csrc[cb + t];
        __syncthreads();

        // ---- pass 1: logits, 4 lanes per edge, fp8 K --------------------
        for (int eb = 0; eb < c; eb += 8) {
            int e8 = eb + el;
            bool act = e8 < c;
            int src = srcs[act ? e8 : 0];
            const uchar_t* kp = kvf8 + (size_t)src * KVF8LD + g * HIDDEN + qr * 24;
            uint2 a0 = *(const uint2*)(kp);
            uint2 a1 = *(const uint2*)(kp + 8);
            uint2 a2 = *(const uint2*)(kp + 16);
            const float* qb = &Qs[g * HIDDEN + qr * 24];
            unsigned int uu[6] = {a0.x, a0.y, a1.x, a1.y, a2.x, a2.y};
            float p = 0.f;
            #pragma unroll
            for (int k2 = 0; k2 < 6; k2++) {
                f32x2 lo = __builtin_amdgcn_cvt_pk_f32_fp8(uu[k2], false);
                f32x2 hi = __builtin_amdgcn_cvt_pk_f32_fp8(uu[k2], true);
                p += lo[0] * qb[4 * k2]     + lo[1] * qb[4 * k2 + 1]
                   + hi[0] * qb[4 * k2 + 2] + hi[1] * qb[4 * k2 + 3];
            }
            p += __shfl_xor(p, 1, 32);
            p += __shfl_xor(p, 2, 32);
            if (act && qr == 0) wbuf[e8 * NH + g] = p * qa;
        }
        __syncthreads();

        // ---- fused softmax: head g handled by its 32 lanes --------------
        {
            float logit = (lane < c) ? wbuf[lane * NH + g] : -1e30f;
            float cm = logit;
            #pragma unroll
            for (int o = 16; o; o >>= 1) cm = fmaxf(cm, __shfl_xor(cm, o, 32));
            cm = fmaxf(cm, m[g]);
            float wv = (lane < c) ? __expf(logit - cm) : 0.f;
            if (lane < c) wbuf[lane * NH + g] = wv;
            float lp = wv;
            #pragma unroll
            for (int o = 16; o; o >>= 1) lp += __shfl_xor(lp, o, 32);
            if (lane == 0) {
                float sc = __expf(m[g] - cm);
                scale[g] = sc;
                l[g] = l[g] * sc + lp;
                m[g] = cm;
            }
        }
        __syncthreads();

        // ---- pass 2: fp8 V aggregation, unroll-4 register staging -------
        if (t < 144) {
            float sc = scale[hh];
            #pragma unroll
            for (int j = 0; j < 4; j++) a[j] *= sc;
            int e = 0;
            for (; e + 4 <= c; e += 4) {
                unsigned int r[4];
                #pragma unroll
                for (int j = 0; j < 4; j++)
                    r[j] = *(const unsigned int*)(vbase + (size_t)srcs[e + j] * KVF8LD);
                #pragma unroll
                for (int j = 0; j < 4; j++) {
                    float w2 = wbuf[(e + j) * NH + hh];
                    f32x2 lo = __builtin_amdgcn_cvt_pk_f32_fp8(r[j], false);
                    f32x2 hi = __builtin_amdgcn_cvt_pk_f32_fp8(r[j], true);
                    a[0] += w2 * lo[0];
                    a[1] += w2 * lo[1];
                    a[2] += w2 * hi[0];
                    a[3] += w2 * hi[1];
                }
            }
            for (; e < c; e++) {
                unsigned int r = *(const unsigned int*)(vbase + (size_t)srcs[e] * KVF8LD);
                float w2 = wbuf[e * NH + hh];
                f32x2 lo = __builtin_amdgcn_cvt_pk_f32_fp8(r, false);
                f32x2 hi = __builtin_amdgcn_cvt_pk_f32_fp8(r, true);
                a[0] += w2 * lo[0];
                a[1] += w2 * lo[1];
                a[2] += w2 * hi[0];
                a[3] += w2 * hi[1];
            }
        }
    }

    if (t < NH) linv[t] = (l[t] > 0.f) ? 1.0f / l[t] : 0.f;
    __syncthreads();
    if (t < 144) {
        float li = linv[hh];
        #pragma unroll
        for (int j = 0; j < 4; j++) arr[d4 + j] = a[j] * li;
    }
    __syncthreads();

    if (t < HIDDEN) {
        float s = (arr[t] + arr[HIDDEN + t] + arr[2 * HIDDEN + t] +
                   arr[3 * HIDDEN + t] + arr[4 * HIDDEN + t] + arr[5 * HIDDEN + t])
                  * (1.0f / 6.0f);
        s += bfs(qk[576 + t]);   // skip connection S (bf16, offset 576)
        s = fmaxf(s, 0.0f);
        hb[n * HIDDEN + t] = f2bf(s);
        hf[n * HIDDEN + t] = s;
    }
}

// ---------------------------------------------------------------------------
// Head with fused mean-pool: block g sums its contiguous node range.
// ---------------------------------------------------------------------------
__global__ __launch_bounds__(128) void k_head(
    const float* __restrict__ hf, const int* __restrict__ gbound,
    const float* __restrict__ fc1w, const float* __restrict__ fc1b,
    const float* __restrict__ fc2w, const float* __restrict__ fc2b,
    const float* __restrict__ arcw, float* __restrict__ out)
{
    int g = blockIdx.x, t = threadIdx.x;
    __shared__ float v0[HIDDEN], v1[HIDDEN], v2[HIDDEN];
    __shared__ float gnorm;
    const int s0 = gbound[g], s1 = gbound[g + 1];
    float cnt = fmaxf((float)(s1 - s0), 1.0f);
    if (t < HIDDEN) {
        float s = 0.f;
        for (int n = s0; n < s1; n++) s += hf[(size_t)n * HIDDEN + t];
        v0[t] = s / cnt;
    }
    __syncthreads();
    if (t < HIDDEN) {
        float s = fc1b[t];
        for (int k = 0; k < HIDDEN; k++) s += v0[k] * fc1w[k * HIDDEN + t];
        v1[t] = fmaxf(s, 0.f);
    }
    __syncthreads();
    if (t < HIDDEN) {
        float s = fc2b[t];
        for (int k = 0; k < HIDDEN; k++) s += v1[k] * fc2w[k * HIDDEN + t];
        v2[t] = fmaxf(s, 0.f);
    }
    __syncthreads();
    if (t == 0) {
        float s = 0.f;
        for (int k = 0; k < HIDDEN; k++) s += v2[k] * v2[k];
        gnorm = sqrtf(s) + 1e-12f;
    }
    __syncthreads();
    if (t < NCLS) {
        float dot = 0.f, wn = 0.f;
        const float* wr = arcw + (size_t)t * HIDDEN;
        for (int k = 0; k < HIDDEN; k++) {
            float w = wr[k];
            dot += w * v2[k];
            wn  += w * w;
        }
        out[g * NCLS + t] = 30.0f * dot / (gnorm * (sqrtf(wn) + 1e-12f));
    }
}

// ---------------------------------------------------------------------------
extern "C" void kernel_launch(void* const* d_in, const int* in_sizes, int n_in,
                              void* d_out, int out_size, void* d_ws, size_t ws_size,
                              hipStream_t stream)
{
    (void)in_sizes; (void)n_in; (void)out_size; (void)ws_size;

    const float* x     = (const float*)d_in[0];
    const int*   ei    = (const int*)d_in[1];
    const int*   batch = (const int*)d_in[2];
    const float* Wq1 = (const float*)d_in[3];  const float* bq1 = (const float*)d_in[4];
    const float* Wk1 = (const float*)d_in[5];  const float* bk1 = (const float*)d_in[6];
    const float* Wv1 = (const float*)d_in[7];  const float* bv1 = (const float*)d_in[8];
    const float* Ws1 = (const float*)d_in[9];  const float* bs1 = (const float*)d_in[10];
    const float* Wq_r = (const float*)d_in[11]; const float* bq_r = (const float*)d_in[12];
    const float* Wk_r = (const float*)d_in[13]; const float* bk_r = (const float*)d_in[14];
    const float* Wv_r = (const float*)d_in[15]; const float* bv_r = (const float*)d_in[16];
    const float* Ws_r = (const float*)d_in[17]; const float* bs_r = (const float*)d_in[18];
    const float* fc1w = (const float*)d_in[19]; const float* fc1b = (const float*)d_in[20];
    const float* fc2w = (const float*)d_in[21]; const float* fc2b = (const float*)d_in[22];
    const float* arcw = (const float*)d_in[23];
    float* out = (float*)d_out;

    const int* esrc = ei;
    const int* edst = ei + N_EDGES;

    char* base = (char*)d_ws;
    size_t off = 0;
    auto alloc = [&](size_t bytes) -> void* {
        off = (off + 255) & ~(size_t)255;
        void* p = base + off;
        off += bytes;
        return p;
    };
    ushort_t* kvqs = (ushort_t*)alloc((size_t)N_NODES * LDROW * 2);  // 28.2 MB
    uchar_t*  kvf8 = (uchar_t*)alloc((size_t)N_NODES * KVF8LD);      // 23.0 MB
    ushort_t* xb  = (ushort_t*)alloc((size_t)N_NODES * DIM_IN * 2);
    ushort_t* hb0 = (ushort_t*)alloc((size_t)N_NODES * HIDDEN * 2);
    ushort_t* hb1 = (ushort_t*)alloc((size_t)N_NODES * HIDDEN * 2);
    float*    hf  = (float*)alloc((size_t)N_NODES * HIDDEN * 4);
    ushort_t* Wb0 = (ushort_t*)alloc((size_t)DIM_IN * NALL * 2);
    ushort_t* Wbr = (ushort_t*)alloc((size_t)4 * HIDDEN * NALL * 2);
    int*   deg     = (int*)alloc(N_NODES * 4);
    int*   row_ptr = (int*)alloc((N_NODES + 1) * 4);
    int*   cursor  = (int*)alloc(N_NODES * 4);
    int*   csrc    = (int*)alloc(N_EDGES * 4);
    int*   gbound  = (int*)alloc((NGRAPH + 1) * 4);

    // prep: x cast | degree | graph boundaries (one launch) + weight cast
    hipMemsetAsync(deg, 0, N_NODES * 4, stream);
    k_prep<<<PREP_CVT_BLOCKS + PREP_DEG_BLOCKS + PREP_GB_BLOCKS, 256, 0, stream>>>(
        x, xb, edst, deg, batch, gbound);
    {
        dim3 gw((DIM_IN * NALL + 255) / 256, 5);
        k_cvt_wT_all<<<gw, 256, 0, stream>>>(Wq1, Wk1, Wv1, Ws1,
                                             Wq_r, Wk_r, Wv_r, Ws_r, Wb0, Wbr);
    }
    k_scan<<<1, 1024, 0, stream>>>(deg, row_ptr, cursor);
    k_scatter<<<(N_EDGES + 255) / 256, 256, 0, stream>>>(esrc, edst, cursor, csrc);

    const ushort_t* Ain = xb;
    ushort_t* hbcur = hb0;
    for (int L = 0; L < 5; L++) {
        const ushort_t* Wb = (L == 0) ? Wb0 : (Wbr + (size_t)(L - 1) * HIDDEN * NALL);
        const float *bq, *bk, *bv, *bs;
        if (L == 0) { bq = bq1; bk = bk1; bv = bv1; bs = bs1; }
        else {
            int i = L - 1;
            bq = bq_r + (size_t)i * HD; bk = bk_r + (size_t)i * HD;
            bv = bv_r + (size_t)i * HD; bs = bs_r + (size_t)i * HIDDEN;
        }
        dim3 g(19, (N_NODES + 255) / 256);
        if (L == 0)
            gemm_qkvs_mfma<DIM_IN><<<g, 256, 0, stream>>>(Ain, N_NODES, Wb,
                                                          bq, bk, bv, bs, kvqs, kvf8);
        else
            gemm_qkvs_mfma<HIDDEN><<<g, 256, 0, stream>>>(Ain, N_NODES, Wb,
                                                          bq, bk, bv, bs, kvqs, kvf8);
        node_attn<<<N_NODES, 192, 0, stream>>>(kvqs, kvf8, row_ptr, csrc, hbcur, hf);
        Ain = hbcur;
        hbcur = (hbcur == hb0) ? hb1 : hb0;
    }

    k_head<<<NGRAPH, 128, 0, stream>>>(hf, gbound, fc1w, fc1b, fc2w, fc2b, arcw, out);
}

// Round 17
// 526.591 us; speedup vs baseline: 1.0345x; 1.0345x over previous
//
#include <hip/hip_runtime.h>
#include <math.h>

#define N_NODES 20000
#define N_EDGES 160000
#define DIM_IN  128
#define HIDDEN  96
#define NH      6
#define HD      576      // NH*HIDDEN
#define LDROW   704      // bf16 row stride: Q(576)|S(96)|pad(32) = 11 lines
#define KVF8LD  1152     // fp8 row stride BYTES: K(576)|V(576) = 9 lines
#define NALL    1824     // concat QKVS weight cols
#define NGRAPH  512
#define NCLS    128
#define CHUNK   32       // edges per softmax chunk
#define SLD     104      // bf16 LDS stage row stride (ushorts)
#define BSTR    112      // fp8 LDS stage row stride (bytes, mult of 16)

typedef unsigned short ushort_t;
typedef unsigned char uchar_t;
typedef __attribute__((ext_vector_type(8))) short bf16x8;
typedef __attribute__((ext_vector_type(4))) float f32x4;
typedef __attribute__((ext_vector_type(2))) float f32x2;

static __device__ __forceinline__ ushort_t f2bf(float f) {
    unsigned int u = __float_as_uint(f);
    return (ushort_t)((u + 0x7fffu + ((u >> 16) & 1u)) >> 16);  // RNE
}
static __device__ __forceinline__ float bfs(ushort_t u) { return __uint_as_float((unsigned int)u << 16); }
static __device__ __forceinline__ float bflo(unsigned int u) { return __uint_as_float(u << 16); }
static __device__ __forceinline__ float bfhi(unsigned int u) { return __uint_as_float(u & 0xffff0000u); }

// ---------------------------------------------------------------------------
// Fused prep: x->bf16 cast | edge degree histogram | graph boundaries.
// ---------------------------------------------------------------------------
#define PREP_CVT_BLOCKS 10000   // 20000*128/256
#define PREP_DEG_BLOCKS 625     // 160000/256
#define PREP_GB_BLOCKS  3       // ceil((NGRAPH+1)/256)
__global__ void k_prep(const float* __restrict__ x, ushort_t* __restrict__ xb,
                       const int* __restrict__ edst, int* __restrict__ deg,
                       const int* __restrict__ batch, int* __restrict__ gbound)
{
    int b = blockIdx.x;
    if (b < PREP_CVT_BLOCKS) {
        int i = b * 256 + threadIdx.x;
        if (i < N_NODES * DIM_IN) xb[i] = f2bf(x[i]);
    } else if (b < PREP_CVT_BLOCKS + PREP_DEG_BLOCKS) {
        int e = (b - PREP_CVT_BLOCKS) * 256 + threadIdx.x;
        if (e < N_EDGES) atomicAdd(&deg[edst[e]], 1);
    } else {
        int g = (b - PREP_CVT_BLOCKS - PREP_DEG_BLOCKS) * 256 + threadIdx.x;
        if (g <= NGRAPH) {
            int lo = 0, hi = N_NODES;
            while (lo < hi) {
                int mid = (lo + hi) >> 1;
                if (batch[mid] < g) lo = mid + 1; else hi = mid;
            }
            gbound[g] = lo;
        }
    }
}

// All 5 layers' transposed concat bf16 weights in one launch. grid.y = layer.
__global__ void k_cvt_wT_all(
    const float* __restrict__ Wq1, const float* __restrict__ Wk1,
    const float* __restrict__ Wv1, const float* __restrict__ Ws1,
    const float* __restrict__ Wq_r, const float* __restrict__ Wk_r,
    const float* __restrict__ Wv_r, const float* __restrict__ Ws_r,
    ushort_t* __restrict__ Wb0, ushort_t* __restrict__ Wbr)
{
    const int L = blockIdx.y;
    const int K = (L == 0) ? DIM_IN : HIDDEN;
    int i = blockIdx.x * blockDim.x + threadIdx.x;
    if (i >= K * NALL) return;
    const float *Wq, *Wk, *Wv, *Ws; ushort_t* dst;
    if (L == 0) { Wq = Wq1; Wk = Wk1; Wv = Wv1; Ws = Ws1; dst = Wb0; }
    else {
        int j = L - 1;
        Wq = Wq_r + (size_t)j * HIDDEN * HD; Wk = Wk_r + (size_t)j * HIDDEN * HD;
        Wv = Wv_r + (size_t)j * HIDDEN * HD; Ws = Ws_r + (size_t)j * HIDDEN * HIDDEN;
        dst = Wbr + (size_t)j * HIDDEN * NALL;
    }
    int n = i / K, k = i - n * K;
    float v;
    if (n < 576)       v = Wq[(size_t)k * HD + n];
    else if (n < 1152) v = Wk[(size_t)k * HD + (n - 576)];
    else if (n < 1728) v = Wv[(size_t)k * HD + (n - 1152)];
    else               v = Ws[(size_t)k * HIDDEN + (n - 1728)];
    dst[i] = f2bf(v);
}

// ---------------------------------------------------------------------------
// bf16 MFMA fused QKVS projection (R14 structure — best measured).
// 128x96 tile, 4 waves (2x2). B staged in LDS; A direct from global.
// Output staged through the same LDS after a barrier. K/V regions (rb 6..17)
// emit fp8-e4m3 into kvf8 [K|V]; Q/S bf16 into kvqs [Q|S].
// ---------------------------------------------------------------------------
template<int KDIM>
__global__ __launch_bounds__(256) void gemm_qkvs_mfma(
    const ushort_t* __restrict__ A, int M,
    const ushort_t* __restrict__ WbT,
    const float* __restrict__ bq, const float* __restrict__ bk,
    const float* __restrict__ bv, const float* __restrict__ bs,
    ushort_t* __restrict__ kvqs, uchar_t* __restrict__ kvf8)
{
    constexpr int LDB = KDIM + 8;       // padded B stride
    constexpr int K8  = KDIM >> 3;
    __shared__ __align__(16) ushort_t smem[128 * SLD];   // 26.6 KB
    const int t    = threadIdx.x;
    const int lane = t & 63;
    const int w    = t >> 6;
    const int wm   = w & 1, wn = w >> 1;
    const int quad = lane >> 4;
    const int l16  = lane & 15;
    const int m0   = blockIdx.y * 128;
    const int rb   = blockIdx.x;          // 0..18
    const int n0   = rb * 96;

    // cooperative B stage: 96 cols x KDIM, contiguous uint4 copies
    for (int idx = t; idx < 96 * K8; idx += 256) {
        int c = idx / K8, kc = idx - c * K8;
        uint4 v = *(const uint4*)(WbT + (size_t)(n0 + c) * KDIM + kc * 8);
        *(uint4*)(&smem[c * LDB + kc * 8]) = v;
    }

    // direct-global A fragment pointers (row-clamped for OOB M)
    const ushort_t* Arow[4];
    #pragma unroll
    for (int i = 0; i < 4; i++) {
        int row = m0 + wm * 64 + i * 16 + l16;
        row = min(row, M - 1);
        Arow[i] = A + (size_t)row * KDIM + quad * 8;
    }
    __syncthreads();

    f32x4 acc[4][3] = {};
    #pragma unroll
    for (int ks = 0; ks < KDIM; ks += 32) {
        bf16x8 af[4], bfv[3];
        #pragma unroll
        for (int i = 0; i < 4; i++) af[i] = *(const bf16x8*)(Arow[i] + ks);
        #pragma unroll
        for (int j = 0; j < 3; j++)
            bfv[j] = *(const bf16x8*)(&smem[(wn * 48 + j * 16 + l16) * LDB + ks + quad * 8]);
        #pragma unroll
        for (int i = 0; i < 4; i++)
            #pragma unroll
            for (int j = 0; j < 3; j++)
                acc[i][j] = __builtin_amdgcn_mfma_f32_16x16x32_bf16(af[i], bfv[j], acc[i][j], 0, 0, 0);
    }

    // region select (boundaries are multiples of 96)
    int region; const float* biasp;
    if (rb < 6)       { region = 0; biasp = bq; }
    else if (rb < 12) { region = 1; biasp = bk; }
    else if (rb < 18) { region = 2; biasp = bv; }
    else              { region = 3; biasp = bs; }
    const int colbase = (region == 3) ? 0 : (rb - region * 6) * 96;
    float bj[3];
    #pragma unroll
    for (int j = 0; j < 3; j++) bj[j] = biasp[colbase + wn * 48 + j * 16 + l16];

    __syncthreads();   // done reading B from smem; safe to overwrite

    if (region == 1 || region == 2) {
        // ---- K/V: fp8-e4m3 byte stage + cooperative 16B stores ---------
        uchar_t* bstage = (uchar_t*)smem;
        #pragma unroll
        for (int i = 0; i < 4; i++) {
            #pragma unroll
            for (int r = 0; r < 4; r++) {
                int row = wm * 64 + i * 16 + quad * 4 + r;
                #pragma unroll
                for (int j = 0; j < 3; j++) {
                    float v = acc[i][j][r] + bj[j];
                    int pk = __builtin_amdgcn_cvt_pk_fp8_f32(v, v, 0, false);
                    bstage[row * BSTR + wn * 48 + j * 16 + l16] = (uchar_t)(pk & 0xff);
                }
            }
        }
        __syncthreads();
        const int c0 = (rb - 6) * 96;   // 0..1056 spans K|V contiguously
        for (int idx = t; idx < 128 * 6; idx += 256) {
            int r = idx / 6, v4 = idx - r * 6;
            int row = m0 + r;
            if (row < M)
                *(uint4*)(kvf8 + (size_t)row * KVF8LD + c0 + v4 * 16) =
                    *(const uint4*)(bstage + r * BSTR + v4 * 16);
        }
    } else {
        // ---- Q/S: bf16 stage + cooperative 16B stores ------------------
        int dstoff = (region == 0) ? n0 : 576;
        #pragma unroll
        for (int i = 0; i < 4; i++) {
            #pragma unroll
            for (int r = 0; r < 4; r++) {
                int row = wm * 64 + i * 16 + quad * 4 + r;
                #pragma unroll
                for (int j = 0; j < 3; j++)
                    smem[row * SLD + wn * 48 + j * 16 + l16] = f2bf(acc[i][j][r] + bj[j]);
            }
        }
        __syncthreads();
        for (int idx = t; idx < 128 * 12; idx += 256) {
            int r = idx / 12, v = idx - r * 12;
            int row = m0 + r;
            if (row < M)
                *(uint4*)(kvqs + (size_t)row * LDROW + dstoff + v * 8) =
                    *(const uint4*)(&smem[r * SLD + v * 8]);
        }
    }
}

// ---------------------------------------------------------------------------
// CSR construction (scan + scatter; degree done in k_prep)
// ---------------------------------------------------------------------------
__global__ __launch_bounds__(1024) void k_scan(const int* __restrict__ deg,
                                               int* __restrict__ row_ptr,
                                               int* __restrict__ cursor)
{
    __shared__ int part[1024];
    int t = threadIdx.x;
    const int chunk = (N_NODES + 1023) / 1024;  // 20
    int b = t * chunk;
    int s = 0;
    for (int i = 0; i < chunk; i++)
        if (b + i < N_NODES) s += deg[b + i];
    part[t] = s;
    __syncthreads();
    for (int o = 1; o < 1024; o <<= 1) {
        int v = (t >= o) ? part[t - o] : 0;
        __syncthreads();
        part[t] += v;
        __syncthreads();
    }
    int run = part[t] - s;
    for (int i = 0; i < chunk; i++) {
        if (b + i < N_NODES) {
            row_ptr[b + i] = run;
            cursor[b + i]  = run;
            run += deg[b + i];
        }
    }
    if (t == 1023) row_ptr[N_NODES] = part[1023];
}

__global__ void k_scatter(const int* __restrict__ esrc, const int* __restrict__ edst,
                          int* __restrict__ cursor, int* __restrict__ csrc)
{
    int e = blockIdx.x * blockDim.x + threadIdx.x;
    if (e < N_EDGES) {
        int pos = atomicAdd(&cursor[edst[e]], 1);
        csrc[pos] = esrc[e];
    }
}

// ---------------------------------------------------------------------------
// Fused per-destination-node attention. fp8 K (pass 1) + fp8 V (pass 2).
// V for the first 8 edges of each chunk is prefetched into 8 VGPRs (fp8 =
// 4 B/edge) right after srcs, so K and V loads are in flight before the
// softmax barrier. Output: bf16 hb only.
// ---------------------------------------------------------------------------
__global__ __launch_bounds__(192) void node_attn(
    const ushort_t* __restrict__ kvqs, const uchar_t* __restrict__ kvf8,
    const int* __restrict__ row_ptr, const int* __restrict__ csrc,
    ushort_t* __restrict__ hb)
{
    const int n = blockIdx.x;
    const int t = threadIdx.x;
    const int lane = t & 31;
    const int g = t >> 5;              // head group 0..5
    const int el = lane >> 2;          // edge slot 0..7
    const int qr = lane & 3;           // quarter 0..3

    __shared__ float Qs[HD];
    __shared__ float wbuf[CHUNK * NH];
    __shared__ int   srcs[CHUNK];
    __shared__ float m[NH], l[NH], scale[NH], linv[NH];
    __shared__ float arr[HD];

    const int beg = row_ptr[n], end = row_ptr[n + 1];
    const ushort_t* qk = kvqs + (size_t)n * LDROW;

    // vectorized Q stage: 72 threads x uint4 (8 bf16 each)
    if (t < 72) {
        uint4 v = *(const uint4*)(qk + t * 8);
        unsigned int uu[4] = {v.x, v.y, v.z, v.w};
        #pragma unroll
        for (int j = 0; j < 4; j++) {
            Qs[t * 8 + 2 * j]     = bflo(uu[j]);
            Qs[t * 8 + 2 * j + 1] = bfhi(uu[j]);
        }
    }
    if (t < NH) { m[t] = -1e30f; l[t] = 0.f; }

    // pass-2 ownership: t<144 owns d = 4t..4t+3 (all in head hh)
    const int d4 = 4 * t;
    const int hh = d4 / HIDDEN;        // valid for t<144
    float a[4] = {0.f, 0.f, 0.f, 0.f};
    const float qa = 0.10206207261596577f; // 1/sqrt(96)
    const uchar_t* vbase = kvf8 + 576 + d4;   // V at byte offset 576

    for (int cb = beg; cb < end; cb += CHUNK) {
        const int c = min(CHUNK, end - cb);
        __syncthreads();
        if (t < c) srcs[t] = csrc[cb + t];
        __syncthreads();

        // ---- V prefetch: first 8 edges, fp8 = 4 B/edge (8 VGPRs) --------
        unsigned int vpre[8];
        if (t < 144) {
            #pragma unroll
            for (int j = 0; j < 8; j++) {
                int e = min(j, c - 1);
                vpre[j] = *(const unsigned int*)(vbase + (size_t)srcs[e] * KVF8LD);
            }
        }

        // ---- pass 1: logits, 4 lanes per edge, fp8 K --------------------
        for (int eb = 0; eb < c; eb += 8) {
            int e8 = eb + el;
            bool act = e8 < c;
            int src = srcs[act ? e8 : 0];
            const uchar_t* kp = kvf8 + (size_t)src * KVF8LD + g * HIDDEN + qr * 24;
            uint2 a0 = *(const uint2*)(kp);
            uint2 a1 = *(const uint2*)(kp + 8);
            uint2 a2 = *(const uint2*)(kp + 16);
            const float* qb = &Qs[g * HIDDEN + qr * 24];
            unsigned int uu[6] = {a0.x, a0.y, a1.x, a1.y, a2.x, a2.y};
            float p = 0.f;
            #pragma unroll
            for (int k2 = 0; k2 < 6; k2++) {
                f32x2 lo = __builtin_amdgcn_cvt_pk_f32_fp8(uu[k2], false);
                f32x2 hi = __builtin_amdgcn_cvt_pk_f32_fp8(uu[k2], true);
                p += lo[0] * qb[4 * k2]     + lo[1] * qb[4 * k2 + 1]
                   + hi[0] * qb[4 * k2 + 2] + hi[1] * qb[4 * k2 + 3];
            }
            p += __shfl_xor(p, 1, 32);
            p += __shfl_xor(p, 2, 32);
            if (act && qr == 0) wbuf[e8 * NH + g] = p * qa;
        }
        __syncthreads();

        // ---- fused softmax: head g handled by its 32 lanes --------------
        {
            float logit = (lane < c) ? wbuf[lane * NH + g] : -1e30f;
            float cm = logit;
            #pragma unroll
            for (int o = 16; o; o >>= 1) cm = fmaxf(cm, __shfl_xor(cm, o, 32));
            cm = fmaxf(cm, m[g]);
            float wv = (lane < c) ? __expf(logit - cm) : 0.f;
            if (lane < c) wbuf[lane * NH + g] = wv;
            float lp = wv;
            #pragma unroll
            for (int o = 16; o; o >>= 1) lp += __shfl_xor(lp, o, 32);
            if (lane == 0) {
                float sc = __expf(m[g] - cm);
                scale[g] = sc;
                l[g] = l[g] * sc + lp;
                m[g] = cm;
            }
        }
        __syncthreads();

        // ---- pass 2: fp8 V aggregation -----------------------------------
        if (t < 144) {
            float sc = scale[hh];
            #pragma unroll
            for (int j = 0; j < 4; j++) a[j] *= sc;
            // prefetched edges (compile-time indices, runtime guard)
            #pragma unroll
            for (int j = 0; j < 8; j++) {
                if (j < c) {
                    float w2 = wbuf[j * NH + hh];
                    f32x2 lo = __builtin_amdgcn_cvt_pk_f32_fp8(vpre[j], false);
                    f32x2 hi = __builtin_amdgcn_cvt_pk_f32_fp8(vpre[j], true);
                    a[0] += w2 * lo[0];
                    a[1] += w2 * lo[1];
                    a[2] += w2 * hi[0];
                    a[3] += w2 * hi[1];
                }
            }
            // remainder via memory, unroll-4 staging
            int e = 8;
            for (; e + 4 <= c; e += 4) {
                unsigned int r[4];
                #pragma unroll
                for (int j = 0; j < 4; j++)
                    r[j] = *(const unsigned int*)(vbase + (size_t)srcs[e + j] * KVF8LD);
                #pragma unroll
                for (int j = 0; j < 4; j++) {
                    float w2 = wbuf[(e + j) * NH + hh];
                    f32x2 lo = __builtin_amdgcn_cvt_pk_f32_fp8(r[j], false);
                    f32x2 hi = __builtin_amdgcn_cvt_pk_f32_fp8(r[j], true);
                    a[0] += w2 * lo[0];
                    a[1] += w2 * lo[1];
                    a[2] += w2 * hi[0];
                    a[3] += w2 * hi[1];
                }
            }
            for (; e < c; e++) {
                unsigned int r = *(const unsigned int*)(vbase + (size_t)srcs[e] * KVF8LD);
                float w2 = wbuf[e * NH + hh];
                f32x2 lo = __builtin_amdgcn_cvt_pk_f32_fp8(r, false);
                f32x2 hi = __builtin_amdgcn_cvt_pk_f32_fp8(r, true);
                a[0] += w2 * lo[0];
                a[1] += w2 * lo[1];
                a[2] += w2 * hi[0];
                a[3] += w2 * hi[1];
            }
        }
    }

    if (t < NH) linv[t] = (l[t] > 0.f) ? 1.0f / l[t] : 0.f;
    __syncthreads();
    if (t < 144) {
        float li = linv[hh];
        #pragma unroll
        for (int j = 0; j < 4; j++) arr[d4 + j] = a[j] * li;
    }
    __syncthreads();

    if (t < HIDDEN) {
        float s = (arr[t] + arr[HIDDEN + t] + arr[2 * HIDDEN + t] +
                   arr[3 * HIDDEN + t] + arr[4 * HIDDEN + t] + arr[5 * HIDDEN + t])
                  * (1.0f / 6.0f);
        s += bfs(qk[576 + t]);   // skip connection S (bf16, offset 576)
        s = fmaxf(s, 0.0f);
        hb[n * HIDDEN + t] = f2bf(s);
    }
}

// ---------------------------------------------------------------------------
// Head with fused mean-pool: block g sums its contiguous node range (bf16 h).
// ---------------------------------------------------------------------------
__global__ __launch_bounds__(128) void k_head(
    const ushort_t* __restrict__ hb, const int* __restrict__ gbound,
    const float* __restrict__ fc1w, const float* __restrict__ fc1b,
    const float* __restrict__ fc2w, const float* __restrict__ fc2b,
    const float* __restrict__ arcw, float* __restrict__ out)
{
    int g = blockIdx.x, t = threadIdx.x;
    __shared__ float v0[HIDDEN], v1[HIDDEN], v2[HIDDEN];
    __shared__ float gnorm;
    const int s0 = gbound[g], s1 = gbound[g + 1];
    float cnt = fmaxf((float)(s1 - s0), 1.0f);
    if (t < HIDDEN) {
        float s = 0.f;
        for (int n = s0; n < s1; n++) s += bfs(hb[(size_t)n * HIDDEN + t]);
        v0[t] = s / cnt;
    }
    __syncthreads();
    if (t < HIDDEN) {
        float s = fc1b[t];
        for (int k = 0; k < HIDDEN; k++) s += v0[k] * fc1w[k * HIDDEN + t];
        v1[t] = fmaxf(s, 0.f);
    }
    __syncthreads();
    if (t < HIDDEN) {
        float s = fc2b[t];
        for (int k = 0; k < HIDDEN; k++) s += v1[k] * fc2w[k * HIDDEN + t];
        v2[t] = fmaxf(s, 0.f);
    }
    __syncthreads();
    if (t == 0) {
        float s = 0.f;
        for (int k = 0; k < HIDDEN; k++) s += v2[k] * v2[k];
        gnorm = sqrtf(s) + 1e-12f;
    }
    __syncthreads();
    if (t < NCLS) {
        float dot = 0.f, wn = 0.f;
        const float* wr = arcw + (size_t)t * HIDDEN;
        for (int k = 0; k < HIDDEN; k++) {
            float w = wr[k];
            dot += w * v2[k];
            wn  += w * w;
        }
        out[g * NCLS + t] = 30.0f * dot / (gnorm * (sqrtf(wn) + 1e-12f));
    }
}

// ---------------------------------------------------------------------------
extern "C" void kernel_launch(void* const* d_in, const int* in_sizes, int n_in,
                              void* d_out, int out_size, void* d_ws, size_t ws_size,
                              hipStream_t stream)
{
    (void)in_sizes; (void)n_in; (void)out_size; (void)ws_size;

    const float* x     = (const float*)d_in[0];
    const int*   ei    = (const int*)d_in[1];
    const int*   batch = (const int*)d_in[2];
    const float* Wq1 = (const float*)d_in[3];  const float* bq1 = (const float*)d_in[4];
    const float* Wk1 = (const float*)d_in[5];  const float* bk1 = (const float*)d_in[6];
    const float* Wv1 = (const float*)d_in[7];  const float* bv1 = (const float*)d_in[8];
    const float* Ws1 = (const float*)d_in[9];  const float* bs1 = (const float*)d_in[10];
    const float* Wq_r = (const float*)d_in[11]; const float* bq_r = (const float*)d_in[12];
    const float* Wk_r = (const float*)d_in[13]; const float* bk_r = (const float*)d_in[14];
    const float* Wv_r = (const float*)d_in[15]; const float* bv_r = (const float*)d_in[16];
    const float* Ws_r = (const float*)d_in[17]; const float* bs_r = (const float*)d_in[18];
    const float* fc1w = (const float*)d_in[19]; const float* fc1b = (const float*)d_in[20];
    const float* fc2w = (const float*)d_in[21]; const float* fc2b = (const float*)d_in[22];
    const float* arcw = (const float*)d_in[23];
    float* out = (float*)d_out;

    const int* esrc = ei;
    const int* edst = ei + N_EDGES;

    char* base = (char*)d_ws;
    size_t off = 0;
    auto alloc = [&](size_t bytes) -> void* {
        off = (off + 255) & ~(size_t)255;
        void* p = base + off;
        off += bytes;
        return p;
    };
    ushort_t* kvqs = (ushort_t*)alloc((size_t)N_NODES * LDROW * 2);  // 28.2 MB
    uchar_t*  kvf8 = (uchar_t*)alloc((size_t)N_NODES * KVF8LD);      // 23.0 MB
    ushort_t* xb  = (ushort_t*)alloc((size_t)N_NODES * DIM_IN * 2);
    ushort_t* hb0 = (ushort_t*)alloc((size_t)N_NODES * HIDDEN * 2);
    ushort_t* hb1 = (ushort_t*)alloc((size_t)N_NODES * HIDDEN * 2);
    ushort_t* Wb0 = (ushort_t*)alloc((size_t)DIM_IN * NALL * 2);
    ushort_t* Wbr = (ushort_t*)alloc((size_t)4 * HIDDEN * NALL * 2);
    int*   deg     = (int*)alloc(N_NODES * 4);
    int*   row_ptr = (int*)alloc((N_NODES + 1) * 4);
    int*   cursor  = (int*)alloc(N_NODES * 4);
    int*   csrc    = (int*)alloc(N_EDGES * 4);
    int*   gbound  = (int*)alloc((NGRAPH + 1) * 4);

    // prep: x cast | degree | graph boundaries (one launch) + weight cast
    hipMemsetAsync(deg, 0, N_NODES * 4, stream);
    k_prep<<<PREP_CVT_BLOCKS + PREP_DEG_BLOCKS + PREP_GB_BLOCKS, 256, 0, stream>>>(
        x, xb, edst, deg, batch, gbound);
    {
        dim3 gw((DIM_IN * NALL + 255) / 256, 5);
        k_cvt_wT_all<<<gw, 256, 0, stream>>>(Wq1, Wk1, Wv1, Ws1,
                                             Wq_r, Wk_r, Wv_r, Ws_r, Wb0, Wbr);
    }
    k_scan<<<1, 1024, 0, stream>>>(deg, row_ptr, cursor);
    k_scatter<<<(N_EDGES + 255) / 256, 256, 0, stream>>>(esrc, edst, cursor, csrc);

    const ushort_t* Ain = xb;
    ushort_t* hbcur = hb0;
    for (int L = 0; L < 5; L++) {
        const ushort_t* Wb = (L == 0) ? Wb0 : (Wbr + (size_t)(L - 1) * HIDDEN * NALL);
        const float *bq, *bk, *bv, *bs;
        if (L == 0) { bq = bq1; bk = bk1; bv = bv1; bs = bs1; }
        else {
            int i = L - 1;
            bq = bq_r + (size_t)i * HD; bk = bk_r + (size_t)i * HD;
            bv = bv_r + (size_t)i * HD; bs = bs_r + (size_t)i * HIDDEN;
        }
        dim3 g(19, (N_NODES + 127) / 128);
        if (L == 0)
            gemm_qkvs_mfma<DIM_IN><<<g, 256, 0, stream>>>(Ain, N_NODES, Wb,
                                                          bq, bk, bv, bs, kvqs, kvf8);
        else
            gemm_qkvs_mfma<HIDDEN><<<g, 256, 0, stream>>>(Ain, N_NODES, Wb,
                                                          bq, bk, bv, bs, kvqs, kvf8);
        node_attn<<<N_NODES, 192, 0, stream>>>(kvqs, kvf8, row_ptr, csrc, hbcur);
        Ain = hbcur;
        hbcur = (hbcur == hb0) ? hb1 : hb0;
    }

    k_head<<<NGRAPH, 128, 0, stream>>>(hbcur == hb0 ? hb1 : hb0, gbound,
                                       fc1w, fc1b, fc2w, fc2b, arcw, out);
}